// Round 9
// baseline (190.600 us; speedup 1.0000x reference)
//
#include <hip/hip_runtime.h>
#include <hip/hip_bf16.h>
#include <math.h>

#define N_NODES 50000
#define N_EDGES 600000
#define N_GRAPHS 512
#define DIM 128
#define OUTD 64
#define EPSV 1e-6f
#define BSTRIDE 64     // bucket slots per node; mean deg 12, P(deg>64) ~ 0
#define EBLK 2344      // ceil(N_EDGES/256)
#define PREP_BLK 64    // 16384/256 covers W-split; gstart inside

typedef __attribute__((ext_vector_type(8))) short bf16x8;
typedef __attribute__((ext_vector_type(4))) float f32x4;

__device__ __forceinline__ float sgn(float v) {
    return (v > 0.f) ? 1.f : ((v < 0.f) ? -1.f : 0.f);
}

__device__ __forceinline__ float cube_signed(float v) {
    float m = fabsf(v) + EPSV;
    return sgn(v) * m * m * m;
}

__device__ __forceinline__ float cbrt_pos(float m) {
    return exp2f(log2f(m) * (1.0f / 3.0f));
}

__device__ __forceinline__ unsigned short f2bf(float f) {
    unsigned u = __float_as_uint(f);
    unsigned r = (u + 0x7fff + ((u >> 16) & 1)) >> 16;   // RNE
    return (unsigned short)r;
}

__device__ __forceinline__ float bf2f(unsigned short h) {
    return __uint_as_float(((unsigned)h) << 16);
}

// Wide gather: lane&15 = feature octet (16B), lane>>4 = edge slot.
// Each uint4 load instruction fetches 4 edges x 256B = 1KB. 16 edges in
// flight per chunk with only 4 VMEM instructions. After the loop, acc[8]
// holds this lane's partial sums (features sub*8..sub*8+7) over edges
// congruent to grp mod 4; caller must reduce across grp (xor 16, xor 32).
__device__ __forceinline__ void gather_acc8(const unsigned* __restrict__ T32,
                                            const int* __restrict__ bucket,
                                            int cnt, int lane, float acc[8]) {
    #pragma unroll
    for (int j = 0; j < 8; j++) acc[j] = 0.f;
    if (cnt <= 0) return;
    int myidx = bucket[lane];      // coalesced: all indices for this node
    int sub = lane & 15, grp = lane >> 4;
    for (int i = 0; i < cnt; i += 16) {
        uint4 u[4];
        #pragma unroll
        for (int c = 0; c < 4; c++) {
            int eid = i + c * 4 + grp;
            int eidc = eid < cnt - 1 ? eid : cnt - 1;
            int s = __shfl(myidx, eidc, 64);
            u[c] = *(const uint4*)(T32 + (size_t)s * 64 + sub * 4);
        }
        #pragma unroll
        for (int c = 0; c < 4; c++) {
            int eid = i + c * 4 + grp;
            bool ok = eid < cnt;
            unsigned w0 = ok ? u[c].x : 0u;
            unsigned w1 = ok ? u[c].y : 0u;
            unsigned w2 = ok ? u[c].z : 0u;
            unsigned w3 = ok ? u[c].w : 0u;
            acc[0] += __uint_as_float(w0 << 16);
            acc[1] += __uint_as_float(w0 & 0xffff0000u);
            acc[2] += __uint_as_float(w1 << 16);
            acc[3] += __uint_as_float(w1 & 0xffff0000u);
            acc[4] += __uint_as_float(w2 << 16);
            acc[5] += __uint_as_float(w2 & 0xffff0000u);
            acc[6] += __uint_as_float(w3 << 16);
            acc[7] += __uint_as_float(w3 & 0xffff0000u);
        }
    }
    #pragma unroll
    for (int j = 0; j < 8; j++) {
        acc[j] += __shfl_xor(acc[j], 16, 64);
        acc[j] += __shfl_xor(acc[j], 32, 64);
    }
}

// ---- build: bucket CSR fill + W hi/lo split + graph segment starts ---------

__global__ void build(const int* __restrict__ src, const int* __restrict__ dst,
                      int* __restrict__ deg, int* __restrict__ csr,
                      const float* __restrict__ W1, const float* __restrict__ W2,
                      unsigned short* __restrict__ W1hi, unsigned short* __restrict__ W1lo,
                      unsigned short* __restrict__ W2hi, unsigned short* __restrict__ W2lo,
                      const int* __restrict__ batch, int* __restrict__ gstart) {
    int b = blockIdx.x;
    if (b < EBLK) {
        int e = b * 256 + threadIdx.x;
        if (e < N_EDGES) {
            int d = dst[e];
            int slot = atomicAdd(&deg[d], 1);
            if (slot < BSTRIDE) csr[d * BSTRIDE + slot] = src[e];
        }
    } else {
        int i = (b - EBLK) * 256 + threadIdx.x;
        if (i < DIM * DIM) {
            float w = W1[i];
            unsigned short h = f2bf(w);
            W1hi[i] = h;
            W1lo[i] = f2bf(w - bf2f(h));
            w = W2[i];
            h = f2bf(w);
            W2hi[i] = h;
            W2lo[i] = f2bf(w - bf2f(h));
        }
        if (i <= N_GRAPHS) {
            int lo = 0, hi = N_NODES;
            while (lo < hi) {
                int mid = (lo + hi) >> 1;
                if (batch[mid] < i) lo = mid + 1; else hi = mid;
            }
            gstart[i] = lo;
        }
    }
}

// ---- Linear+cube via split-bf16 MFMA: T = cube_signed(X @ W^T + B), bf16 ---

__global__ __launch_bounds__(256) void linear_cube_mfma(const float* __restrict__ X,
                                                        const unsigned short* __restrict__ Whi,
                                                        const unsigned short* __restrict__ Wlo,
                                                        const float* __restrict__ B,
                                                        unsigned short* __restrict__ T) {
    int wave = threadIdx.x >> 6;
    int lane = threadIdx.x & 63;
    int tile = blockIdx.x * 4 + wave;
    if (tile >= N_NODES / 16) return;
    int n0 = tile * 16;
    int r = lane & 15;    // A-row (node) on load side; B/D column (output)
    int g = lane >> 4;    // k-group

    bf16x8 xh[4], xl[4];
    const float* xrow = X + (size_t)(n0 + r) * DIM + g * 8;
    #pragma unroll
    for (int kb = 0; kb < 4; kb++) {
        float4 a = *(const float4*)(xrow + kb * 32);
        float4 b = *(const float4*)(xrow + kb * 32 + 4);
        float v[8] = {a.x, a.y, a.z, a.w, b.x, b.y, b.z, b.w};
        #pragma unroll
        for (int j = 0; j < 8; j++) {
            unsigned short h = f2bf(v[j]);
            float rem = v[j] - bf2f(h);
            xh[kb][j] = (short)h;
            xl[kb][j] = (short)f2bf(rem);
        }
    }

    #pragma unroll
    for (int ct = 0; ct < 8; ct++) {
        const unsigned short* whbase = Whi + (size_t)(ct * 16 + r) * DIM + g * 8;
        const unsigned short* wlbase = Wlo + (size_t)(ct * 16 + r) * DIM + g * 8;
        f32x4 acc = {0.f, 0.f, 0.f, 0.f};
        #pragma unroll
        for (int kb = 0; kb < 4; kb++) {
            bf16x8 wh = *(const bf16x8*)(whbase + kb * 32);
            bf16x8 wl = *(const bf16x8*)(wlbase + kb * 32);
            acc = __builtin_amdgcn_mfma_f32_16x16x32_bf16(xh[kb], wh, acc, 0, 0, 0);
            acc = __builtin_amdgcn_mfma_f32_16x16x32_bf16(xl[kb], wh, acc, 0, 0, 0);
            acc = __builtin_amdgcn_mfma_f32_16x16x32_bf16(xh[kb], wl, acc, 0, 0, 0);
        }
        float bias = B[ct * 16 + r];
        #pragma unroll
        for (int q = 0; q < 4; q++) {
            int node = g * 4 + q;   // D row = (lane>>4)*4 + reg  [m89]
            float h = acc[q] + bias;
            T[(size_t)(n0 + node) * DIM + ct * 16 + r] = f2bf(cube_signed(h));
        }
    }
}

// ---- Fused: aggregate(layer1)+ReLU -> LDS -> linear2+cube -> T2 ------------
// 512 threads / 8 waves per 16-node tile. Phase 1: 2 nodes per wave with
// wide gather. Phase 2: 1 column-tile per wave.

__global__ __launch_bounds__(512) void agg_linear_cube(const unsigned* __restrict__ T32,
                                                       const int* __restrict__ deg,
                                                       const int* __restrict__ csr,
                                                       const unsigned short* __restrict__ Whi,
                                                       const unsigned short* __restrict__ Wlo,
                                                       const float* __restrict__ B,
                                                       unsigned short* __restrict__ Tout) {
    __shared__ float Pl[16][132];
    int wave = threadIdx.x >> 6;
    int lane = threadIdx.x & 63;
    int n0 = blockIdx.x * 16;
    int sub = lane & 15, grp = lane >> 4;

    // phase 1: aggregate + cbrt + relu (2 nodes per wave)
    #pragma unroll
    for (int q = 0; q < 2; q++) {
        int row = wave * 2 + q;
        int nd = n0 + row;
        int d = deg[nd];
        int cnt = d < BSTRIDE ? d : BSTRIDE;
        float acc[8];
        gather_acc8(T32, csr + (size_t)nd * BSTRIDE, cnt, lane, acc);
        float c = (float)(d > 1 ? d : 1);
        float m0 = acc[2 * grp] / c, m1 = acc[2 * grp + 1] / c;
        float r0 = fmaxf(sgn(m0) * cbrt_pos(fabsf(m0) + EPSV), 0.f);
        float r1 = fmaxf(sgn(m1) * cbrt_pos(fabsf(m1) + EPSV), 0.f);
        *(float2*)&Pl[row][sub * 8 + grp * 2] = make_float2(r0, r1);
    }
    __syncthreads();

    // phase 2: hi/lo split from LDS (float4 reads), MFMA, cube, store bf16
    int r = lane & 15;
    int g = lane >> 4;
    bf16x8 xh[4], xl[4];
    #pragma unroll
    for (int kb = 0; kb < 4; kb++) {
        float4 va = *(const float4*)&Pl[r][kb * 32 + g * 8];
        float4 vb = *(const float4*)&Pl[r][kb * 32 + g * 8 + 4];
        float v[8] = {va.x, va.y, va.z, va.w, vb.x, vb.y, vb.z, vb.w};
        #pragma unroll
        for (int j = 0; j < 8; j++) {
            unsigned short h = f2bf(v[j]);
            xh[kb][j] = (short)h;
            xl[kb][j] = (short)f2bf(v[j] - bf2f(h));
        }
    }
    int ct = wave;
    const unsigned short* whbase = Whi + (size_t)(ct * 16 + r) * DIM + g * 8;
    const unsigned short* wlbase = Wlo + (size_t)(ct * 16 + r) * DIM + g * 8;
    f32x4 acc = {0.f, 0.f, 0.f, 0.f};
    #pragma unroll
    for (int kb = 0; kb < 4; kb++) {
        bf16x8 wh = *(const bf16x8*)(whbase + kb * 32);
        bf16x8 wl = *(const bf16x8*)(wlbase + kb * 32);
        acc = __builtin_amdgcn_mfma_f32_16x16x32_bf16(xh[kb], wh, acc, 0, 0, 0);
        acc = __builtin_amdgcn_mfma_f32_16x16x32_bf16(xl[kb], wh, acc, 0, 0, 0);
        acc = __builtin_amdgcn_mfma_f32_16x16x32_bf16(xh[kb], wl, acc, 0, 0, 0);
    }
    float bias = B[ct * 16 + r];
    #pragma unroll
    for (int q = 0; q < 4; q++) {
        int node = g * 4 + q;
        float h = acc[q] + bias;
        Tout[(size_t)(n0 + node) * DIM + ct * 16 + r] = f2bf(cube_signed(h));
    }
}

// ---- Conv aggregate (layer 2): mean of bf16 cubes -> signed cbrt -> P fp32 -

__global__ __launch_bounds__(256) void aggregate(const unsigned* __restrict__ T32,
                                                 const int* __restrict__ deg,
                                                 const int* __restrict__ csr,
                                                 float* __restrict__ P) {
    int nd = blockIdx.x * 4 + (threadIdx.x >> 6);
    if (nd >= N_NODES) return;
    int lane = threadIdx.x & 63;
    int sub = lane & 15, grp = lane >> 4;
    int d = deg[nd];
    int cnt = d < BSTRIDE ? d : BSTRIDE;
    float acc[8];
    gather_acc8(T32, csr + (size_t)nd * BSTRIDE, cnt, lane, acc);
    float c = (float)(d > 1 ? d : 1);
    float m0 = acc[2 * grp] / c, m1 = acc[2 * grp + 1] / c;
    float r0 = sgn(m0) * cbrt_pos(fabsf(m0) + EPSV);
    float r1 = sgn(m1) * cbrt_pos(fabsf(m1) + EPSV);
    *(float2*)(P + (size_t)nd * DIM + sub * 8 + grp * 2) = make_float2(r0, r1);
}

// ---- Fused graph pool + final linear ---------------------------------------

__global__ __launch_bounds__(128) void pool_final(const float* __restrict__ P,
                                                  const int* __restrict__ gstart,
                                                  const float* __restrict__ Wout,
                                                  const float* __restrict__ bout,
                                                  float* __restrict__ out) {
    __shared__ float R[DIM];
    __shared__ float partial[128];
    int g = blockIdx.x, f = threadIdx.x;
    int s = gstart[g], e = gstart[g + 1];
    float acc = 0.f;
    for (int i = s; i < e; i++) {
        float v = P[(size_t)i * DIM + f];
        float m = fabsf(v) + EPSV;
        acc += sgn(v) * m * m;
    }
    int cnt = e - s;
    float c = (float)(cnt > 1 ? cnt : 1);
    float mean = acc / c;
    R[f] = sgn(mean) * sqrtf(fabsf(mean) + EPSV);
    __syncthreads();

    int o = f & 63;
    int half = f >> 6;
    const float4* W4 = (const float4*)Wout + o * 32 + half * 16;
    const float4* R4 = (const float4*)R + half * 16;
    float a = 0.f;
    #pragma unroll
    for (int k = 0; k < 16; k++) {
        float4 w = W4[k];
        float4 r = R4[k];
        a += r.x * w.x + r.y * w.y + r.z * w.z + r.w * w.w;
    }
    partial[f] = a;
    __syncthreads();
    if (f < OUTD) out[(size_t)g * OUTD + f] = bout[f] + partial[f] + partial[f + 64];
}

// ---- launch ----------------------------------------------------------------

extern "C" void kernel_launch(void* const* d_in, const int* in_sizes, int n_in,
                              void* d_out, int out_size, void* d_ws, size_t ws_size,
                              hipStream_t stream) {
    const float* x    = (const float*)d_in[0];
    const float* W1   = (const float*)d_in[1];
    const float* b1   = (const float*)d_in[2];
    const float* W2   = (const float*)d_in[3];
    const float* b2   = (const float*)d_in[4];
    const float* Wout = (const float*)d_in[5];
    const float* bout = (const float*)d_in[6];
    const int* edge   = (const int*)d_in[7];
    const int* batch  = (const int*)d_in[8];
    const int* srcp = edge;
    const int* dstp = edge + N_EDGES;
    float* out = (float*)d_out;

    char* ws = (char*)d_ws;
    size_t off = 0;
    auto alloc = [&](size_t bytes) -> char* {
        char* p = ws + off;
        off += (bytes + 255) / 256 * 256;
        return p;
    };
    unsigned short* T1 = (unsigned short*)alloc((size_t)N_NODES * DIM * 2);
    unsigned short* T2 = (unsigned short*)alloc((size_t)N_NODES * DIM * 2);
    float* P        = (float*)alloc((size_t)N_NODES * DIM * 4);
    int*   deg      = (int*)alloc((size_t)N_NODES * 4);
    int*   csr      = (int*)alloc((size_t)N_NODES * BSTRIDE * 4);
    int*   gstart   = (int*)alloc((size_t)(N_GRAPHS + 1) * 4);
    unsigned short* W1hi = (unsigned short*)alloc((size_t)DIM * DIM * 2);
    unsigned short* W1lo = (unsigned short*)alloc((size_t)DIM * DIM * 2);
    unsigned short* W2hi = (unsigned short*)alloc((size_t)DIM * DIM * 2);
    unsigned short* W2lo = (unsigned short*)alloc((size_t)DIM * DIM * 2);

    hipMemsetAsync(deg, 0, (size_t)N_NODES * 4, stream);
    build<<<EBLK + PREP_BLK, 256, 0, stream>>>(srcp, dstp, deg, csr,
                                               W1, W2, W1hi, W1lo, W2hi, W2lo,
                                               batch, gstart);

    const int TILES = N_NODES / 16;           // 3125
    const int LBLK = (TILES + 3) / 4;         // 782 blocks x 4 waves
    const int ABLK = (N_NODES + 3) / 4;       // 12500 blocks x 4 waves
    linear_cube_mfma<<<LBLK, 256, 0, stream>>>(x, W1hi, W1lo, b1, T1);
    agg_linear_cube<<<TILES, 512, 0, stream>>>((const unsigned*)T1, deg, csr,
                                               W2hi, W2lo, b2, T2);
    aggregate<<<ABLK, 256, 0, stream>>>((const unsigned*)T2, deg, csr, P);
    pool_final<<<N_GRAPHS, 128, 0, stream>>>(P, gstart, Wout, bout, out);
}

// Round 10
// 187.387 us; speedup vs baseline: 1.0171x; 1.0171x over previous
//
#include <hip/hip_runtime.h>
#include <hip/hip_bf16.h>
#include <math.h>

#define N_NODES 50000
#define N_EDGES 600000
#define N_GRAPHS 512
#define DIM 128
#define OUTD 64
#define EPSV 1e-6f
#define BSTRIDE 64     // bucket slots per node; mean deg 12, P(deg>64) ~ 0
#define EBLK 2344      // ceil(N_EDGES/256)
#define PREP_BLK 64    // 16384/256 covers W-split; gstart inside

typedef __attribute__((ext_vector_type(8))) short bf16x8;
typedef __attribute__((ext_vector_type(4))) float f32x4;

__device__ __forceinline__ float sgn(float v) {
    return (v > 0.f) ? 1.f : ((v < 0.f) ? -1.f : 0.f);
}

__device__ __forceinline__ float cube_signed(float v) {
    float m = fabsf(v) + EPSV;
    return sgn(v) * m * m * m;
}

__device__ __forceinline__ float cbrt_pos(float m) {
    return exp2f(log2f(m) * (1.0f / 3.0f));
}

__device__ __forceinline__ unsigned short f2bf(float f) {
    unsigned u = __float_as_uint(f);
    unsigned r = (u + 0x7fff + ((u >> 16) & 1)) >> 16;   // RNE
    return (unsigned short)r;
}

__device__ __forceinline__ float bf2f(unsigned short h) {
    return __uint_as_float(((unsigned)h) << 16);
}

// Wide padded gather: lane&15 = feature octet (16B), lane>>4 = edge slot.
// Buckets are zero-padded to 16 (index 0 = dummy zero row of T), so there is
// NO masking/clamping in the hot loop: {shfl, addr, dwordx4, unpack, add}.
// acc pairs as float2 to enable v_pk_add_f32.
__device__ __forceinline__ void gather_acc8(const unsigned* __restrict__ T32,
                                            const int* __restrict__ bucket,
                                            int cnt16, int lane, float2 acc[4]) {
    #pragma unroll
    for (int j = 0; j < 4; j++) acc[j] = make_float2(0.f, 0.f);
    if (cnt16 <= 0) return;
    int myidx = bucket[lane];      // coalesced: all indices for this node
    int sub = lane & 15, grp = lane >> 4;
    for (int i = 0; i < cnt16; i += 16) {
        uint4 u[4];
        #pragma unroll
        for (int c = 0; c < 4; c++) {
            int s = __shfl(myidx, i + c * 4 + grp, 64);
            u[c] = *(const uint4*)(T32 + (size_t)s * 64 + sub * 4);
        }
        #pragma unroll
        for (int c = 0; c < 4; c++) {
            acc[0].x += __uint_as_float(u[c].x << 16);
            acc[0].y += __uint_as_float(u[c].x & 0xffff0000u);
            acc[1].x += __uint_as_float(u[c].y << 16);
            acc[1].y += __uint_as_float(u[c].y & 0xffff0000u);
            acc[2].x += __uint_as_float(u[c].z << 16);
            acc[2].y += __uint_as_float(u[c].z & 0xffff0000u);
            acc[3].x += __uint_as_float(u[c].w << 16);
            acc[3].y += __uint_as_float(u[c].w & 0xffff0000u);
        }
    }
    #pragma unroll
    for (int j = 0; j < 4; j++) {
        acc[j].x += __shfl_xor(acc[j].x, 16, 64);
        acc[j].y += __shfl_xor(acc[j].y, 16, 64);
        acc[j].x += __shfl_xor(acc[j].x, 32, 64);
        acc[j].y += __shfl_xor(acc[j].y, 32, 64);
    }
}

// ---- build: bucket CSR fill (+1-shifted indices) + W split + gstart --------
// csr must be zeroed (memsetAsync) before this kernel; slot value 0 = dummy.

__global__ void build(const int* __restrict__ src, const int* __restrict__ dst,
                      int* __restrict__ deg, int* __restrict__ csr,
                      const float* __restrict__ W1, const float* __restrict__ W2,
                      unsigned short* __restrict__ W1hi, unsigned short* __restrict__ W1lo,
                      unsigned short* __restrict__ W2hi, unsigned short* __restrict__ W2lo,
                      const int* __restrict__ batch, int* __restrict__ gstart,
                      unsigned* __restrict__ T1z, unsigned* __restrict__ T2z) {
    int b = blockIdx.x;
    if (b < EBLK) {
        int e = b * 256 + threadIdx.x;
        if (e < N_EDGES) {
            int d = dst[e];
            int slot = atomicAdd(&deg[d], 1);
            if (slot < BSTRIDE) csr[d * BSTRIDE + slot] = src[e] + 1;
        }
    } else {
        int i = (b - EBLK) * 256 + threadIdx.x;
        if (i < 64) { T1z[i] = 0u; T2z[i] = 0u; }   // dummy zero row 0
        if (i < DIM * DIM) {
            float w = W1[i];
            unsigned short h = f2bf(w);
            W1hi[i] = h;
            W1lo[i] = f2bf(w - bf2f(h));
            w = W2[i];
            h = f2bf(w);
            W2hi[i] = h;
            W2lo[i] = f2bf(w - bf2f(h));
        }
        if (i <= N_GRAPHS) {
            int lo = 0, hi = N_NODES;
            while (lo < hi) {
                int mid = (lo + hi) >> 1;
                if (batch[mid] < i) lo = mid + 1; else hi = mid;
            }
            gstart[i] = lo;
        }
    }
}

// ---- Linear+cube via split-bf16 MFMA: T[n+1] = cube(X @ W^T + B), bf16 -----

__global__ __launch_bounds__(256) void linear_cube_mfma(const float* __restrict__ X,
                                                        const unsigned short* __restrict__ Whi,
                                                        const unsigned short* __restrict__ Wlo,
                                                        const float* __restrict__ B,
                                                        unsigned short* __restrict__ T) {
    int wave = threadIdx.x >> 6;
    int lane = threadIdx.x & 63;
    int tile = blockIdx.x * 4 + wave;
    if (tile >= N_NODES / 16) return;
    int n0 = tile * 16;
    int r = lane & 15;    // A-row (node) on load side; B/D column (output)
    int g = lane >> 4;    // k-group

    bf16x8 xh[4], xl[4];
    const float* xrow = X + (size_t)(n0 + r) * DIM + g * 8;
    #pragma unroll
    for (int kb = 0; kb < 4; kb++) {
        float4 a = *(const float4*)(xrow + kb * 32);
        float4 b = *(const float4*)(xrow + kb * 32 + 4);
        float v[8] = {a.x, a.y, a.z, a.w, b.x, b.y, b.z, b.w};
        #pragma unroll
        for (int j = 0; j < 8; j++) {
            unsigned short h = f2bf(v[j]);
            float rem = v[j] - bf2f(h);
            xh[kb][j] = (short)h;
            xl[kb][j] = (short)f2bf(rem);
        }
    }

    #pragma unroll
    for (int ct = 0; ct < 8; ct++) {
        const unsigned short* whbase = Whi + (size_t)(ct * 16 + r) * DIM + g * 8;
        const unsigned short* wlbase = Wlo + (size_t)(ct * 16 + r) * DIM + g * 8;
        f32x4 acc = {0.f, 0.f, 0.f, 0.f};
        #pragma unroll
        for (int kb = 0; kb < 4; kb++) {
            bf16x8 wh = *(const bf16x8*)(whbase + kb * 32);
            bf16x8 wl = *(const bf16x8*)(wlbase + kb * 32);
            acc = __builtin_amdgcn_mfma_f32_16x16x32_bf16(xh[kb], wh, acc, 0, 0, 0);
            acc = __builtin_amdgcn_mfma_f32_16x16x32_bf16(xl[kb], wh, acc, 0, 0, 0);
            acc = __builtin_amdgcn_mfma_f32_16x16x32_bf16(xh[kb], wl, acc, 0, 0, 0);
        }
        float bias = B[ct * 16 + r];
        #pragma unroll
        for (int q = 0; q < 4; q++) {
            int node = g * 4 + q;   // D row = (lane>>4)*4 + reg  [m89]
            float h = acc[q] + bias;
            T[(size_t)(n0 + node + 1) * DIM + ct * 16 + r] = f2bf(cube_signed(h));
        }
    }
}

// ---- Fused: aggregate(layer1)+ReLU -> split -> LDS bf16 planes -> MFMA -----
// 512 threads / 8 waves per 16-node tile. Phase 1: 2 nodes/wave gather, then
// bf16 hi/lo split ONCE (4 elems/lane) into packed LDS planes. Phase 2 reads
// MFMA fragments directly (ds_read_b128, zero split VALU).

__global__ __launch_bounds__(512) void agg_linear_cube(const unsigned* __restrict__ T32,
                                                       const int* __restrict__ deg,
                                                       const int* __restrict__ csr,
                                                       const unsigned short* __restrict__ Whi,
                                                       const unsigned short* __restrict__ Wlo,
                                                       const float* __restrict__ B,
                                                       unsigned short* __restrict__ Tout) {
    __shared__ __attribute__((aligned(16))) unsigned Phi[16][68];
    __shared__ __attribute__((aligned(16))) unsigned Plo[16][68];
    int wave = threadIdx.x >> 6;
    int lane = threadIdx.x & 63;
    int n0 = blockIdx.x * 16;
    int sub = lane & 15, grp = lane >> 4;

    // phase 1: aggregate + cbrt + relu + hi/lo split (2 nodes per wave)
    #pragma unroll
    for (int q = 0; q < 2; q++) {
        int row = wave * 2 + q;
        int nd = n0 + row;
        int d = deg[nd];
        int cnt = d < BSTRIDE ? d : BSTRIDE;
        int cnt16 = (cnt + 15) & ~15;
        float2 acc[4];
        gather_acc8(T32, csr + (size_t)nd * BSTRIDE, cnt16, lane, acc);
        float c = (float)(d > 1 ? d : 1);
        float m0 = acc[grp >> 1].x, m1 = acc[grp >> 1].y;   // wrong pair? no:
        // lane's feature pair f2 = sub*4+grp -> features (2*f2, 2*f2+1),
        // which live in acc word index grp (x=even feat, y=odd feat)
        m0 = (grp == 0 ? acc[0].x : grp == 1 ? acc[1].x : grp == 2 ? acc[2].x : acc[3].x) / c;
        m1 = (grp == 0 ? acc[0].y : grp == 1 ? acc[1].y : grp == 2 ? acc[2].y : acc[3].y) / c;
        float r0 = fmaxf(sgn(m0) * cbrt_pos(fabsf(m0) + EPSV), 0.f);
        float r1 = fmaxf(sgn(m1) * cbrt_pos(fabsf(m1) + EPSV), 0.f);
        unsigned short h0 = f2bf(r0), h1 = f2bf(r1);
        unsigned short l0 = f2bf(r0 - bf2f(h0)), l1 = f2bf(r1 - bf2f(h1));
        Phi[row][sub * 4 + grp] = (unsigned)h0 | ((unsigned)h1 << 16);
        Plo[row][sub * 4 + grp] = (unsigned)l0 | ((unsigned)l1 << 16);
    }
    __syncthreads();

    // phase 2: fragments straight from LDS planes
    int r = lane & 15;
    int g = lane >> 4;
    bf16x8 xh[4], xl[4];
    #pragma unroll
    for (int kb = 0; kb < 4; kb++) {
        xh[kb] = *(const bf16x8*)&Phi[r][kb * 16 + g * 4];
        xl[kb] = *(const bf16x8*)&Plo[r][kb * 16 + g * 4];
    }
    int ct = wave;
    const unsigned short* whbase = Whi + (size_t)(ct * 16 + r) * DIM + g * 8;
    const unsigned short* wlbase = Wlo + (size_t)(ct * 16 + r) * DIM + g * 8;
    f32x4 acc = {0.f, 0.f, 0.f, 0.f};
    #pragma unroll
    for (int kb = 0; kb < 4; kb++) {
        bf16x8 wh = *(const bf16x8*)(whbase + kb * 32);
        bf16x8 wl = *(const bf16x8*)(wlbase + kb * 32);
        acc = __builtin_amdgcn_mfma_f32_16x16x32_bf16(xh[kb], wh, acc, 0, 0, 0);
        acc = __builtin_amdgcn_mfma_f32_16x16x32_bf16(xl[kb], wh, acc, 0, 0, 0);
        acc = __builtin_amdgcn_mfma_f32_16x16x32_bf16(xh[kb], wl, acc, 0, 0, 0);
    }
    float bias = B[ct * 16 + r];
    #pragma unroll
    for (int q = 0; q < 4; q++) {
        int node = g * 4 + q;
        float h = acc[q] + bias;
        Tout[(size_t)(n0 + node + 1) * DIM + ct * 16 + r] = f2bf(cube_signed(h));
    }
}

// ---- Conv aggregate (layer 2): mean of bf16 cubes -> signed cbrt -> P fp32 -

__global__ __launch_bounds__(256) void aggregate(const unsigned* __restrict__ T32,
                                                 const int* __restrict__ deg,
                                                 const int* __restrict__ csr,
                                                 float* __restrict__ P) {
    int nd = blockIdx.x * 4 + (threadIdx.x >> 6);
    if (nd >= N_NODES) return;
    int lane = threadIdx.x & 63;
    int sub = lane & 15, grp = lane >> 4;
    int d = deg[nd];
    int cnt = d < BSTRIDE ? d : BSTRIDE;
    int cnt16 = (cnt + 15) & ~15;
    float2 acc[4];
    gather_acc8(T32, csr + (size_t)nd * BSTRIDE, cnt16, lane, acc);
    float c = (float)(d > 1 ? d : 1);
    float m0 = (grp == 0 ? acc[0].x : grp == 1 ? acc[1].x : grp == 2 ? acc[2].x : acc[3].x) / c;
    float m1 = (grp == 0 ? acc[0].y : grp == 1 ? acc[1].y : grp == 2 ? acc[2].y : acc[3].y) / c;
    float r0 = sgn(m0) * cbrt_pos(fabsf(m0) + EPSV);
    float r1 = sgn(m1) * cbrt_pos(fabsf(m1) + EPSV);
    *(float2*)(P + (size_t)nd * DIM + sub * 8 + grp * 2) = make_float2(r0, r1);
}

// ---- Fused graph pool + final linear ---------------------------------------

__global__ __launch_bounds__(128) void pool_final(const float* __restrict__ P,
                                                  const int* __restrict__ gstart,
                                                  const float* __restrict__ Wout,
                                                  const float* __restrict__ bout,
                                                  float* __restrict__ out) {
    __shared__ float R[DIM];
    __shared__ float partial[128];
    int g = blockIdx.x, f = threadIdx.x;
    int s = gstart[g], e = gstart[g + 1];
    float acc = 0.f;
    for (int i = s; i < e; i++) {
        float v = P[(size_t)i * DIM + f];
        float m = fabsf(v) + EPSV;
        acc += sgn(v) * m * m;
    }
    int cnt = e - s;
    float c = (float)(cnt > 1 ? cnt : 1);
    float mean = acc / c;
    R[f] = sgn(mean) * sqrtf(fabsf(mean) + EPSV);
    __syncthreads();

    int o = f & 63;
    int half = f >> 6;
    const float4* W4 = (const float4*)Wout + o * 32 + half * 16;
    const float4* R4 = (const float4*)R + half * 16;
    float a = 0.f;
    #pragma unroll
    for (int k = 0; k < 16; k++) {
        float4 w = W4[k];
        float4 r = R4[k];
        a += r.x * w.x + r.y * w.y + r.z * w.z + r.w * w.w;
    }
    partial[f] = a;
    __syncthreads();
    if (f < OUTD) out[(size_t)g * OUTD + f] = bout[f] + partial[f] + partial[f + 64];
}

// ---- launch ----------------------------------------------------------------

extern "C" void kernel_launch(void* const* d_in, const int* in_sizes, int n_in,
                              void* d_out, int out_size, void* d_ws, size_t ws_size,
                              hipStream_t stream) {
    const float* x    = (const float*)d_in[0];
    const float* W1   = (const float*)d_in[1];
    const float* b1   = (const float*)d_in[2];
    const float* W2   = (const float*)d_in[3];
    const float* b2   = (const float*)d_in[4];
    const float* Wout = (const float*)d_in[5];
    const float* bout = (const float*)d_in[6];
    const int* edge   = (const int*)d_in[7];
    const int* batch  = (const int*)d_in[8];
    const int* srcp = edge;
    const int* dstp = edge + N_EDGES;
    float* out = (float*)d_out;

    char* ws = (char*)d_ws;
    size_t off = 0;
    auto alloc = [&](size_t bytes) -> char* {
        char* p = ws + off;
        off += (bytes + 255) / 256 * 256;
        return p;
    };
    unsigned short* T1 = (unsigned short*)alloc((size_t)(N_NODES + 1) * DIM * 2);
    unsigned short* T2 = (unsigned short*)alloc((size_t)(N_NODES + 1) * DIM * 2);
    float* P        = (float*)alloc((size_t)N_NODES * DIM * 4);
    int*   deg      = (int*)alloc((size_t)N_NODES * 4);
    int*   csr      = (int*)alloc((size_t)N_NODES * BSTRIDE * 4);
    int*   gstart   = (int*)alloc((size_t)(N_GRAPHS + 1) * 4);
    unsigned short* W1hi = (unsigned short*)alloc((size_t)DIM * DIM * 2);
    unsigned short* W1lo = (unsigned short*)alloc((size_t)DIM * DIM * 2);
    unsigned short* W2hi = (unsigned short*)alloc((size_t)DIM * DIM * 2);
    unsigned short* W2lo = (unsigned short*)alloc((size_t)DIM * DIM * 2);

    hipMemsetAsync(deg, 0, (size_t)N_NODES * 4, stream);
    hipMemsetAsync(csr, 0, (size_t)N_NODES * BSTRIDE * 4, stream);
    build<<<EBLK + PREP_BLK, 256, 0, stream>>>(srcp, dstp, deg, csr,
                                               W1, W2, W1hi, W1lo, W2hi, W2lo,
                                               batch, gstart,
                                               (unsigned*)T1, (unsigned*)T2);

    const int TILES = N_NODES / 16;           // 3125
    const int LBLK = (TILES + 3) / 4;         // 782 blocks x 4 waves
    const int ABLK = (N_NODES + 3) / 4;       // 12500 blocks x 4 waves
    linear_cube_mfma<<<LBLK, 256, 0, stream>>>(x, W1hi, W1lo, b1, T1);
    agg_linear_cube<<<TILES, 512, 0, stream>>>((const unsigned*)T1, deg, csr,
                                               W2hi, W2lo, b2, T2);
    aggregate<<<ABLK, 256, 0, stream>>>((const unsigned*)T2, deg, csr, P);
    pool_final<<<N_GRAPHS, 128, 0, stream>>>(P, gstart, Wout, bout, out);
}